// Round 1
// baseline (42672.800 us; speedup 1.0000x reference)
//
#include <hip/hip_runtime.h>

#define NB 16          // batches
#define NPTS 131072    // points per batch
#define NPOINT 1024
#define HID 192
#define OUTC 384
#define BLKS_PER_B 16
#define THREADS_FPS 1024
#define PTS_PER_T (NPTS / BLKS_PER_B / THREADS_FPS)  // 8
#define SENT (~0ull)

// ---------------- FPS ----------------
// 16 blocks per batch, each block owns 8192 points (8/thread, in registers).
// Per iteration: update min_dist, block-argmax of packed (dist_bits<<32 | ~idx),
// cross-block handshake through device-scope atomics in d_ws.
__global__ __launch_bounds__(1024) void fps_kernel(
    const float* __restrict__ points,
    unsigned long long* __restrict__ result,    // [NB][NPOINT-1], init to SENT
    unsigned long long* __restrict__ partials,  // [NB][16]
    unsigned int* __restrict__ counters,        // [NB], init 0
    int* __restrict__ fps_idx)                  // [NB][NPOINT], [b][0]=0 pre-set
{
  const int blk = blockIdx.x;
  const int b = blk >> 4;
  const int r = blk & 15;
  const int t = threadIdx.x;
  const float* __restrict__ P = points + (size_t)b * NPTS * 3;
  const int base = r * (NPTS / BLKS_PER_B);

  float px[PTS_PER_T], py[PTS_PER_T], pz[PTS_PER_T], md[PTS_PER_T];
  unsigned int lowk[PTS_PER_T];
#pragma unroll
  for (int k = 0; k < PTS_PER_T; ++k) {
    int i = base + (k << 10) + t;
    const float* pp = P + (size_t)i * 3;
    px[k] = pp[0]; py[k] = pp[1]; pz[k] = pp[2];
    md[k] = 1e10f;
    lowk[k] = 0xFFFFFFFFu - (unsigned int)i;  // larger low word == smaller idx (first-max tiebreak)
  }

  // first selected index is 0
  float lx = P[0], ly = P[1], lz = P[2];

  __shared__ unsigned long long s_red[16];
  __shared__ unsigned long long s_bcast;

  unsigned long long* res_b = result + (size_t)b * (NPOINT - 1);
  unsigned long long* par_b = partials + b * 16;

  for (int it = 0; it < NPOINT - 1; ++it) {
    unsigned long long best = 0ull;
#pragma unroll
    for (int k = 0; k < PTS_PER_T; ++k) {
      float dx = px[k] - lx;
      float dy = py[k] - ly;
      float dz = pz[k] - lz;
      // numpy op order, no FMA contraction: (dx*dx + dy*dy) + dz*dz
      float d = __fadd_rn(__fadd_rn(__fmul_rn(dx, dx), __fmul_rn(dy, dy)), __fmul_rn(dz, dz));
      float m = fminf(md[k], d);
      md[k] = m;
      unsigned long long key =
          ((unsigned long long)__float_as_uint(m) << 32) | (unsigned long long)lowk[k];
      best = key > best ? key : best;
    }
    // wave (64-lane) reduce, max of u64 keys
#pragma unroll
    for (int off = 32; off > 0; off >>= 1) {
      unsigned int lo = (unsigned int)best, hi = (unsigned int)(best >> 32);
      lo = __shfl_down(lo, off, 64);
      hi = __shfl_down(hi, off, 64);
      unsigned long long o = ((unsigned long long)hi << 32) | (unsigned long long)lo;
      best = o > best ? o : best;
    }
    const int lane = t & 63, wid = t >> 6;
    if (lane == 0) s_red[wid] = best;
    __syncthreads();
    if (t == 0) {
      unsigned long long bb = s_red[0];
#pragma unroll
      for (int w = 1; w < 16; ++w) bb = s_red[w] > bb ? s_red[w] : bb;
      // publish partial, arrive
      __hip_atomic_store(&par_b[r], bb, __ATOMIC_RELEASE, __HIP_MEMORY_SCOPE_AGENT);
      unsigned int arr = __hip_atomic_fetch_add(&counters[b], 1u, __ATOMIC_ACQ_REL,
                                                __HIP_MEMORY_SCOPE_AGENT);
      if (arr == (unsigned int)(it * 16 + 15)) {
        // last to arrive: reduce the 16 partials, publish result for this iteration
        unsigned long long fin = 0ull;
#pragma unroll
        for (int q = 0; q < 16; ++q) {
          unsigned long long pv =
              __hip_atomic_load(&par_b[q], __ATOMIC_ACQUIRE, __HIP_MEMORY_SCOPE_AGENT);
          fin = pv > fin ? pv : fin;
        }
        fps_idx[b * NPOINT + it + 1] = (int)(0xFFFFFFFFu - (unsigned int)(fin & 0xFFFFFFFFull));
        __hip_atomic_store(&res_b[it], fin, __ATOMIC_RELEASE, __HIP_MEMORY_SCOPE_AGENT);
      }
      unsigned long long rv;
      do {
        rv = __hip_atomic_load(&res_b[it], __ATOMIC_ACQUIRE, __HIP_MEMORY_SCOPE_AGENT);
      } while (rv == SENT);
      s_bcast = rv;
    }
    __syncthreads();
    unsigned long long rv = s_bcast;
    int nidx = (int)(0xFFFFFFFFu - (unsigned int)(rv & 0xFFFFFFFFull));
    const float* lp = P + (size_t)nidx * 3;
    lx = lp[0]; ly = lp[1]; lz = lp[2];
  }
}

// ---------------- init ----------------
__global__ void fps_init_kernel(unsigned long long* __restrict__ result,
                                unsigned int* __restrict__ counters,
                                int* __restrict__ fps_idx)
{
  int i = blockIdx.x * blockDim.x + threadIdx.x;
  if (i < NB * (NPOINT - 1)) result[i] = SENT;
  if (i < NB) { counters[i] = 0u; fps_idx[i * NPOINT] = 0; }
}

// ---------------- MLP ----------------
// 4 rows (centers) per block, 384 threads. Phase 1: 384 threads compute
// hidden (2 MLPs x 192) with exact GELU into LDS. Phase 2: thread o
// accumulates output column o for 4 rows x 2 MLPs with coalesced w2 reads.
__global__ __launch_bounds__(384) void mlp_kernel(
    const float* __restrict__ points,
    const int* __restrict__ fps_idx,
    const float* __restrict__ w1t, const float* __restrict__ b1t,
    const float* __restrict__ w2t, const float* __restrict__ b2t,
    const float* __restrict__ w1p, const float* __restrict__ b1p,
    const float* __restrict__ w2p, const float* __restrict__ b2p,
    float* __restrict__ out)
{
  __shared__ float s_c[4][3];
  __shared__ float s_h[2][HID][4];
  const int t = threadIdx.x;
  const int m0 = blockIdx.x * 4;
  if (t < 4) {
    int m = m0 + t;
    int b = m >> 10;
    int idx = fps_idx[m];
    const float* p = points + ((size_t)b * NPTS + (size_t)idx) * 3;
    s_c[t][0] = p[0]; s_c[t][1] = p[1]; s_c[t][2] = p[2];
  }
  __syncthreads();
  {
    const int mlp = t / HID;            // 0 = token, 1 = pos
    const int k = t - mlp * HID;
    const float* w1 = mlp ? w1p : w1t;
    const float* b1 = mlp ? b1p : b1t;
    float wa = w1[k], wb = w1[HID + k], wc = w1[2 * HID + k], bb = b1[k];
#pragma unroll
    for (int r = 0; r < 4; ++r) {
      float z = s_c[r][0] * wa + s_c[r][1] * wb + s_c[r][2] * wc + bb;
      float g = 0.5f * z * (1.0f + erff(z * 0.70710678118654752440f));
      s_h[mlp][k][r] = g;
    }
  }
  __syncthreads();
  const int o = t;
  float acct[4] = {0.f, 0.f, 0.f, 0.f};
  float accp[4] = {0.f, 0.f, 0.f, 0.f};
  const float* w2t_o = w2t + o;
  const float* w2p_o = w2p + o;
#pragma unroll 4
  for (int k = 0; k < HID; ++k) {
    float wt = w2t_o[(size_t)k * OUTC];
    float wp = w2p_o[(size_t)k * OUTC];
    float4 ht = *(const float4*)&s_h[0][k][0];
    float4 hp = *(const float4*)&s_h[1][k][0];
    acct[0] = fmaf(ht.x, wt, acct[0]);
    acct[1] = fmaf(ht.y, wt, acct[1]);
    acct[2] = fmaf(ht.z, wt, acct[2]);
    acct[3] = fmaf(ht.w, wt, acct[3]);
    accp[0] = fmaf(hp.x, wp, accp[0]);
    accp[1] = fmaf(hp.y, wp, accp[1]);
    accp[2] = fmaf(hp.z, wp, accp[2]);
    accp[3] = fmaf(hp.w, wp, accp[3]);
  }
  float bt = b2t[o], bp = b2p[o];
  const size_t posoff = (size_t)NB * NPOINT * OUTC;
#pragma unroll
  for (int rr = 0; rr < 4; ++rr) {
    size_t m = (size_t)(m0 + rr);
    out[m * OUTC + o] = acct[rr] + bt;
    out[posoff + m * OUTC + o] = accp[rr] + bp;
  }
}

extern "C" void kernel_launch(void* const* d_in, const int* in_sizes, int n_in,
                              void* d_out, int out_size, void* d_ws, size_t ws_size,
                              hipStream_t stream)
{
  const float* points = (const float*)d_in[0];
  const float* w1t = (const float*)d_in[1];
  const float* b1t = (const float*)d_in[2];
  const float* w2t = (const float*)d_in[3];
  const float* b2t = (const float*)d_in[4];
  const float* w1p = (const float*)d_in[5];
  const float* b1p = (const float*)d_in[6];
  const float* w2p = (const float*)d_in[7];
  const float* b2p = (const float*)d_in[8];
  float* out = (float*)d_out;

  char* ws = (char*)d_ws;
  unsigned long long* result = (unsigned long long*)(ws + 0);        // 16*1023*8 = 130944 B
  unsigned long long* partials = (unsigned long long*)(ws + 131072); // 2048 B
  unsigned int* counters = (unsigned int*)(ws + 133120);             // 64 B
  int* fps_idx = (int*)(ws + 133632);                                // 65536 B

  hipLaunchKernelGGL(fps_init_kernel, dim3(64), dim3(256), 0, stream,
                     result, counters, fps_idx);

  void* args[5];
  args[0] = (void*)&points;
  args[1] = (void*)&result;
  args[2] = (void*)&partials;
  args[3] = (void*)&counters;
  args[4] = (void*)&fps_idx;
  hipLaunchCooperativeKernel((void*)fps_kernel, dim3(NB * BLKS_PER_B),
                             dim3(THREADS_FPS), args, 0, stream);

  hipLaunchKernelGGL(mlp_kernel, dim3(NB * NPOINT / 4), dim3(384), 0, stream,
                     points, fps_idx, w1t, b1t, w2t, b2t, w1p, b1p, w2p, b2p, out);
}

// Round 2
// 2528.942 us; speedup vs baseline: 16.8738x; 16.8738x over previous
//
#include <hip/hip_runtime.h>

#define NB 16          // batches
#define NPTS 131072    // points per batch
#define NPOINT 1024
#define HID 192
#define OUTC 384
#define BLKS_PER_B 16
#define THREADS_FPS 1024
#define PTS_PER_T (NPTS / BLKS_PER_B / THREADS_FPS)  // 8
#define TAG_INIT 1023u  // never matches: it ranges 0..1022

// ---------------- FPS ----------------
// 16 blocks per batch, 8 points/thread in registers. Per iteration:
//  1. update md, pack (dist<<32 | ~idx), wave shfl reduce, LDS reduce to 16
//  2. lanes 0..15 of wave 0: 4-step shfl_xor -> block best; lane 0 stores it
//     into this block's slot as (dist[63:32] | inv17[31:15] | it[9:0]),
//     relaxed agent scope (the tag IS the synchronization).
//  3. lane t polls slot[t] until tag==it (16 parallel pollers, loads pipeline)
//  4. 4-step shfl_xor over the 16 slot values -> global winner, broadcast via LDS.
// Slots double-buffered on it&1: a block can be at most 1 iteration ahead, so
// it never overwrites a value a slower block still needs. Tags distinguish
// it from it-2 (stale) and from the init value 1023.
__global__ __launch_bounds__(1024) void fps_kernel(
    const float* __restrict__ points,
    unsigned long long* __restrict__ slots,   // [NB][2][16]
    int* __restrict__ fps_idx)                // [NB][NPOINT], [b][0]=0 pre-set
{
  const int blk = blockIdx.x;
  const int b = blk >> 4;
  const int r = blk & 15;
  const int t = threadIdx.x;
  const float* __restrict__ P = points + (size_t)b * NPTS * 3;
  const int base = r * (NPTS / BLKS_PER_B);

  float px[PTS_PER_T], py[PTS_PER_T], pz[PTS_PER_T], md[PTS_PER_T];
  unsigned int lowk[PTS_PER_T];
#pragma unroll
  for (int k = 0; k < PTS_PER_T; ++k) {
    int i = base + (k << 10) + t;
    const float* pp = P + (size_t)i * 3;
    px[k] = pp[0]; py[k] = pp[1]; pz[k] = pp[2];
    md[k] = 1e10f;
    lowk[k] = 0xFFFFFFFFu - (unsigned int)i;  // larger low word == smaller idx (first-max tiebreak)
  }

  // first selected index is 0
  float lx = P[0], ly = P[1], lz = P[2];

  __shared__ unsigned long long s_red[16];
  __shared__ int s_nidx;

  unsigned long long* slot_b = slots + b * 32;  // [2][16]

  for (int it = 0; it < NPOINT - 1; ++it) {
    unsigned long long best = 0ull;
#pragma unroll
    for (int k = 0; k < PTS_PER_T; ++k) {
      float dx = px[k] - lx;
      float dy = py[k] - ly;
      float dz = pz[k] - lz;
      // numpy op order, no FMA contraction: (dx*dx + dy*dy) + dz*dz
      float d = __fadd_rn(__fadd_rn(__fmul_rn(dx, dx), __fmul_rn(dy, dy)), __fmul_rn(dz, dz));
      float m = fminf(md[k], d);
      md[k] = m;
      unsigned long long key =
          ((unsigned long long)__float_as_uint(m) << 32) | (unsigned long long)lowk[k];
      best = key > best ? key : best;
    }
    // wave (64-lane) reduce, max of u64 keys
#pragma unroll
    for (int off = 32; off > 0; off >>= 1) {
      unsigned int lo = (unsigned int)best, hi = (unsigned int)(best >> 32);
      lo = __shfl_down(lo, off, 64);
      hi = __shfl_down(hi, off, 64);
      unsigned long long o = ((unsigned long long)hi << 32) | (unsigned long long)lo;
      best = o > best ? o : best;
    }
    const int lane = t & 63, wid = t >> 6;
    if (lane == 0) s_red[wid] = best;
    __syncthreads();
    if (t < 16) {
      // block-level reduce across the 16 wave partials (lanes 0..15 of wave 0)
      unsigned long long v = s_red[t];
#pragma unroll
      for (int off = 8; off > 0; off >>= 1) {
        unsigned int lo = (unsigned int)v, hi = (unsigned int)(v >> 32);
        lo = __shfl_xor(lo, off, 64);
        hi = __shfl_xor(hi, off, 64);
        unsigned long long o = ((unsigned long long)hi << 32) | (unsigned long long)lo;
        v = o > v ? o : v;
      }
      unsigned long long* buf = slot_b + ((it & 1) << 4);
      if (t == 0) {
        // repack: dist[63:32] | inv17[31:15] | it[9:0]
        unsigned int i = 0xFFFFFFFFu - (unsigned int)v;
        unsigned long long inv17 = (unsigned long long)((NPTS - 1) - i);
        unsigned long long sv = (v & 0xFFFFFFFF00000000ull) | (inv17 << 15) |
                                (unsigned long long)(unsigned int)it;
        __hip_atomic_store(&buf[r], sv, __ATOMIC_RELAXED, __HIP_MEMORY_SCOPE_AGENT);
      }
      // 16 parallel pollers, one slot each; relaxed loads pipeline
      unsigned long long pv;
      do {
        pv = __hip_atomic_load(&buf[t], __ATOMIC_RELAXED, __HIP_MEMORY_SCOPE_AGENT);
      } while ((unsigned int)(pv & 0x3FFull) != (unsigned int)it);
      // global winner across 16 slot values (tags equal -> u64 compare == (dist, inv17))
#pragma unroll
      for (int off = 8; off > 0; off >>= 1) {
        unsigned int lo = (unsigned int)pv, hi = (unsigned int)(pv >> 32);
        lo = __shfl_xor(lo, off, 64);
        hi = __shfl_xor(hi, off, 64);
        unsigned long long o = ((unsigned long long)hi << 32) | (unsigned long long)lo;
        pv = o > pv ? o : pv;
      }
      if (t == 0) {
        int nidx = (int)(NPTS - 1) - (int)((pv >> 15) & 0x1FFFFull);
        s_nidx = nidx;
        if (r == 0) fps_idx[b * NPOINT + it + 1] = nidx;
      }
    }
    __syncthreads();
    int nidx = s_nidx;
    const float* lp = P + (size_t)nidx * 3;
    lx = lp[0]; ly = lp[1]; lz = lp[2];
  }
}

// ---------------- init ----------------
__global__ void fps_init_kernel(unsigned long long* __restrict__ slots,
                                int* __restrict__ fps_idx)
{
  int i = blockIdx.x * blockDim.x + threadIdx.x;
  if (i < NB * 2 * 16) slots[i] = (unsigned long long)TAG_INIT;
  if (i < NB) fps_idx[i * NPOINT] = 0;
}

// ---------------- MLP ----------------
// 4 rows (centers) per block, 384 threads. Phase 1: 384 threads compute
// hidden (2 MLPs x 192) with exact GELU into LDS. Phase 2: thread o
// accumulates output column o for 4 rows x 2 MLPs with coalesced w2 reads.
__global__ __launch_bounds__(384) void mlp_kernel(
    const float* __restrict__ points,
    const int* __restrict__ fps_idx,
    const float* __restrict__ w1t, const float* __restrict__ b1t,
    const float* __restrict__ w2t, const float* __restrict__ b2t,
    const float* __restrict__ w1p, const float* __restrict__ b1p,
    const float* __restrict__ w2p, const float* __restrict__ b2p,
    float* __restrict__ out)
{
  __shared__ float s_c[4][3];
  __shared__ float s_h[2][HID][4];
  const int t = threadIdx.x;
  const int m0 = blockIdx.x * 4;
  if (t < 4) {
    int m = m0 + t;
    int b = m >> 10;
    int idx = fps_idx[m];
    const float* p = points + ((size_t)b * NPTS + (size_t)idx) * 3;
    s_c[t][0] = p[0]; s_c[t][1] = p[1]; s_c[t][2] = p[2];
  }
  __syncthreads();
  {
    const int mlp = t / HID;            // 0 = token, 1 = pos
    const int k = t - mlp * HID;
    const float* w1 = mlp ? w1p : w1t;
    const float* b1 = mlp ? b1p : b1t;
    float wa = w1[k], wb = w1[HID + k], wc = w1[2 * HID + k], bb = b1[k];
#pragma unroll
    for (int r = 0; r < 4; ++r) {
      float z = s_c[r][0] * wa + s_c[r][1] * wb + s_c[r][2] * wc + bb;
      float g = 0.5f * z * (1.0f + erff(z * 0.70710678118654752440f));
      s_h[mlp][k][r] = g;
    }
  }
  __syncthreads();
  const int o = t;
  float acct[4] = {0.f, 0.f, 0.f, 0.f};
  float accp[4] = {0.f, 0.f, 0.f, 0.f};
  const float* w2t_o = w2t + o;
  const float* w2p_o = w2p + o;
#pragma unroll 4
  for (int k = 0; k < HID; ++k) {
    float wt = w2t_o[(size_t)k * OUTC];
    float wp = w2p_o[(size_t)k * OUTC];
    float4 ht = *(const float4*)&s_h[0][k][0];
    float4 hp = *(const float4*)&s_h[1][k][0];
    acct[0] = fmaf(ht.x, wt, acct[0]);
    acct[1] = fmaf(ht.y, wt, acct[1]);
    acct[2] = fmaf(ht.z, wt, acct[2]);
    acct[3] = fmaf(ht.w, wt, acct[3]);
    accp[0] = fmaf(hp.x, wp, accp[0]);
    accp[1] = fmaf(hp.y, wp, accp[1]);
    accp[2] = fmaf(hp.z, wp, accp[2]);
    accp[3] = fmaf(hp.w, wp, accp[3]);
  }
  float bt = b2t[o], bp = b2p[o];
  const size_t posoff = (size_t)NB * NPOINT * OUTC;
#pragma unroll
  for (int rr = 0; rr < 4; ++rr) {
    size_t m = (size_t)(m0 + rr);
    out[m * OUTC + o] = acct[rr] + bt;
    out[posoff + m * OUTC + o] = accp[rr] + bp;
  }
}

extern "C" void kernel_launch(void* const* d_in, const int* in_sizes, int n_in,
                              void* d_out, int out_size, void* d_ws, size_t ws_size,
                              hipStream_t stream)
{
  const float* points = (const float*)d_in[0];
  const float* w1t = (const float*)d_in[1];
  const float* b1t = (const float*)d_in[2];
  const float* w2t = (const float*)d_in[3];
  const float* b2t = (const float*)d_in[4];
  const float* w1p = (const float*)d_in[5];
  const float* b1p = (const float*)d_in[6];
  const float* w2p = (const float*)d_in[7];
  const float* b2p = (const float*)d_in[8];
  float* out = (float*)d_out;

  char* ws = (char*)d_ws;
  unsigned long long* slots = (unsigned long long*)(ws + 0);  // 16*2*16*8 = 4096 B
  int* fps_idx = (int*)(ws + 4096);                           // 16*1024*4 = 65536 B

  hipLaunchKernelGGL(fps_init_kernel, dim3(2), dim3(256), 0, stream,
                     slots, fps_idx);

  void* args[3];
  args[0] = (void*)&points;
  args[1] = (void*)&slots;
  args[2] = (void*)&fps_idx;
  hipLaunchCooperativeKernel((void*)fps_kernel, dim3(NB * BLKS_PER_B),
                             dim3(THREADS_FPS), args, 0, stream);

  hipLaunchKernelGGL(mlp_kernel, dim3(NB * NPOINT / 4), dim3(384), 0, stream,
                     points, fps_idx, w1t, b1t, w2t, b2t, w1p, b1p, w2p, b2p, out);
}